// Round 2
// baseline (313.577 us; speedup 1.0000x reference)
//
#include <hip/hip_runtime.h>
#include <cstdint>
#include <cstddef>

#define BB 4
#define HCC 32
#define WCC 32
#define KCC 1024
#define NCC (HCC*WCC)   /* 1024 */
#define HFF 128
#define WFF 128
#define KFF 256
#define DCC 4
#define NCHUNK 8
#define MCHUNK 128

// ---------------- squared row norms (one wave per row) ----------------
__global__ __launch_bounds__(256) void norms_kernel(
    const float* __restrict__ x0, const float* __restrict__ x1,
    float* __restrict__ o0, float* __restrict__ o1, int rows, int K4) {
  const float* __restrict__ x = blockIdx.y ? x1 : x0;
  float* __restrict__ o = blockIdx.y ? o1 : o0;
  int wave = threadIdx.x >> 6, lane = threadIdx.x & 63;
  int row = blockIdx.x * 4 + wave;
  if (row >= rows) return;
  const float4* __restrict__ p = (const float4*)(x + (size_t)row * ((size_t)K4 * 4));
  float s = 0.f;
  for (int idx = lane; idx < K4; idx += 64) {
    float4 v = p[idx];
    s += v.x*v.x + v.y*v.y + v.z*v.z + v.w*v.w;
  }
  #pragma unroll
  for (int m = 32; m; m >>= 1) s += __shfl_xor(s, m, 64);
  if (lane == 0) o[row] = s;
}

// ---------------- coarse: tiled GEMM + per-chunk argmin ----------------
// grid (NCHUNK=8, 16 n-tiles, B). block 256. tile: 64 queries x 128 cands.
__global__ __launch_bounds__(256) void coarse_kernel(
    const float* __restrict__ f1, const float* __restrict__ fk,
    const float* __restrict__ na, const float* __restrict__ nq,
    float* __restrict__ pval, int* __restrict__ pidx) {
  __shared__ float As[64][36];
  __shared__ float Bs0[32][68];
  __shared__ float Bs1[32][68];

  const int t = threadIdx.x;
  const int chunk = blockIdx.x;
  const int n0 = blockIdx.y * 64;
  const int b = blockIdx.z;
  const int m0 = chunk * MCHUNK;

  const float* __restrict__ Aby = fk + (size_t)b * NCC * KCC;  // queries
  const float* __restrict__ Bby = f1 + (size_t)b * NCC * KCC;  // candidates

  const int lr = t >> 2;          // 0..63
  const int lq = (t & 3) * 4;     // 0,4,8,12

  float acc0[4][4], acc1[4][4];
  #pragma unroll
  for (int i2 = 0; i2 < 4; ++i2)
    #pragma unroll
    for (int j2 = 0; j2 < 4; ++j2) { acc0[i2][j2] = 0.f; acc1[i2][j2] = 0.f; }

  const int tr = t >> 4, tc = t & 15;

  for (int k0 = 0; k0 < KCC; k0 += 32) {
    // A tile 64x32 (row-major, pad 36)
    {
      const float* src = Aby + (size_t)(n0 + lr) * KCC + k0 + lq;
      float4 v0 = *(const float4*)src;
      float4 v1 = *(const float4*)(src + 16);
      *(float4*)&As[lr][lq] = v0;
      *(float4*)&As[lr][lq + 16] = v1;
    }
    // B tiles 2 x (64 cands x 32 k), stored transposed [k][col] pad 68
    {
      const float* src = Bby + (size_t)(m0 + lr) * KCC + k0 + lq;
      float4 v0 = *(const float4*)src;
      float4 v1 = *(const float4*)(src + 16);
      Bs0[lq+0][lr] = v0.x; Bs0[lq+1][lr] = v0.y; Bs0[lq+2][lr] = v0.z; Bs0[lq+3][lr] = v0.w;
      Bs0[lq+16][lr] = v1.x; Bs0[lq+17][lr] = v1.y; Bs0[lq+18][lr] = v1.z; Bs0[lq+19][lr] = v1.w;
      const float* src1 = Bby + (size_t)(m0 + 64 + lr) * KCC + k0 + lq;
      float4 w0 = *(const float4*)src1;
      float4 w1 = *(const float4*)(src1 + 16);
      Bs1[lq+0][lr] = w0.x; Bs1[lq+1][lr] = w0.y; Bs1[lq+2][lr] = w0.z; Bs1[lq+3][lr] = w0.w;
      Bs1[lq+16][lr] = w1.x; Bs1[lq+17][lr] = w1.y; Bs1[lq+18][lr] = w1.z; Bs1[lq+19][lr] = w1.w;
    }
    __syncthreads();

    #pragma unroll
    for (int k4 = 0; k4 < 8; ++k4) {
      float ak[4][4];
      #pragma unroll
      for (int i2 = 0; i2 < 4; ++i2) {
        float4 a4 = *(const float4*)&As[tr*4 + i2][k4*4];
        ak[i2][0] = a4.x; ak[i2][1] = a4.y; ak[i2][2] = a4.z; ak[i2][3] = a4.w;
      }
      #pragma unroll
      for (int kk = 0; kk < 4; ++kk) {
        float4 b0 = *(const float4*)&Bs0[k4*4 + kk][tc*4];
        float4 b1 = *(const float4*)&Bs1[k4*4 + kk][tc*4];
        #pragma unroll
        for (int i2 = 0; i2 < 4; ++i2) {
          float av = ak[i2][kk];
          acc0[i2][0] = fmaf(av, b0.x, acc0[i2][0]);
          acc0[i2][1] = fmaf(av, b0.y, acc0[i2][1]);
          acc0[i2][2] = fmaf(av, b0.z, acc0[i2][2]);
          acc0[i2][3] = fmaf(av, b0.w, acc0[i2][3]);
          acc1[i2][0] = fmaf(av, b1.x, acc1[i2][0]);
          acc1[i2][1] = fmaf(av, b1.y, acc1[i2][1]);
          acc1[i2][2] = fmaf(av, b1.z, acc1[i2][2]);
          acc1[i2][3] = fmaf(av, b1.w, acc1[i2][3]);
        }
      }
    }
    __syncthreads();
  }

  // epilogue: dist = (q2 + a2) - 2*dot, argmin with first-index ties
  float q2[4];
  #pragma unroll
  for (int i2 = 0; i2 < 4; ++i2) q2[i2] = nq[b*NCC + n0 + tr*4 + i2];

  #pragma unroll
  for (int i2 = 0; i2 < 4; ++i2) {
    float bv = 3.0e38f; int bi = 0;
    #pragma unroll
    for (int j2 = 0; j2 < 4; ++j2) {
      int m = m0 + tc*4 + j2;
      float d = (q2[i2] + na[b*NCC + m]) - 2.0f * acc0[i2][j2];
      if (d < bv) { bv = d; bi = m; }
    }
    #pragma unroll
    for (int j2 = 0; j2 < 4; ++j2) {
      int m = m0 + 64 + tc*4 + j2;
      float d = (q2[i2] + na[b*NCC + m]) - 2.0f * acc1[i2][j2];
      if (d < bv) { bv = d; bi = m; }
    }
    // reduce across the 16 tc lanes (lane-contiguous group)
    #pragma unroll
    for (int m = 1; m < 16; m <<= 1) {
      float ov = __shfl_xor(bv, m, 64);
      int oi = __shfl_xor(bi, m, 64);
      if (ov < bv || (ov == bv && oi < bi)) { bv = ov; bi = oi; }
    }
    if (tc == 0) {
      int n = n0 + tr*4 + i2;
      pval[((size_t)b*NCC + n)*NCHUNK + chunk] = bv;
      pidx[((size_t)b*NCC + n)*NCHUNK + chunk] = bi;
    }
  }
}

// ---------------- coarse: combine chunk partials ----------------
__global__ __launch_bounds__(256) void coarse_reduce_kernel(
    const float* __restrict__ pval, const int* __restrict__ pidx,
    int* __restrict__ out) {
  int g = blockIdx.x * 256 + threadIdx.x;
  if (g >= BB * NCC) return;
  float bv = pval[(size_t)g * NCHUNK];
  int bi = pidx[(size_t)g * NCHUNK];
  #pragma unroll
  for (int c = 1; c < NCHUNK; ++c) {
    float v = pval[(size_t)g * NCHUNK + c];
    int ix = pidx[(size_t)g * NCHUNK + c];
    if (v < bv) { bv = v; bi = ix; }   // idx ascending with chunk -> first-min kept
  }
  out[(size_t)g*2]     = bi >> 5;   // // WC
  out[(size_t)g*2 + 1] = bi & 31;   // % WC
}

// ---------------- fine: per-cell 16x144 match, k-chunked LDS staging ----------------
// grid (WC=32, HC=32, B). block 192 = 3 waves. thread tile 4p x 3n.
// Per k-chunk of 32: stage cand[144][32] + query[16][32] in LDS (coalesced),
// inner loop is pure LDS + FMA.
#define FKB 32
__global__ __launch_bounds__(192) void fine_kernel(
    const float* __restrict__ f1, const float* __restrict__ fkf,
    const float* __restrict__ na, const float* __restrict__ nq,
    const int* __restrict__ coarse, int* __restrict__ outf) {
  __shared__ float cs[144][36];      // candidate k-chunk (pad 36 -> 16B aligned rows, 2-way max)
  __shared__ float qs[16][36];       // query k-chunk
  __shared__ float cn[144];          // candidate sq-norms
  __shared__ unsigned cOff[144];     // candidate row base offsets (floats)
  __shared__ unsigned qOff[16];      // query row base offsets
  __shared__ float q2s[16];
  __shared__ int cbr[9], cbc[9];
  __shared__ float rbv[16][48];
  __shared__ int rbi[16][48];

  const int t = threadIdx.x;
  const int j = blockIdx.x, i = blockIdx.y, b = blockIdx.z;

  if (t < 9) {
    int di = t / 3 - 1, dj = t % 3 - 1;
    int y = min(max(i + di, 0), HCC - 1);
    int x = min(max(j + dj, 0), WCC - 1);
    int base = ((b*HCC + y)*WCC + x) * 2;
    cbr[t] = coarse[base];
    cbc[t] = coarse[base + 1];
  }
  if (t < 16) {
    int fr = i*DCC + (t >> 2), fc = j*DCC + (t & 3);
    q2s[t] = nq[((size_t)b*HFF + fr)*WFF + fc];
    qOff[t] = (unsigned)((((unsigned)b*HFF + fr)*WFF + fc) * KFF);
  }
  __syncthreads();
  if (t < 144) {
    int n9 = t >> 4, s = t & 15;
    int row = cbr[n9]*DCC + (s >> 2), col = cbc[n9]*DCC + (s & 3);
    unsigned off = (((unsigned)b*HFF + row)*WFF + col);
    cn[t] = na[off];
    cOff[t] = off * KFF;
  }

  const int tp = t & 3;        // p-tile (rows tp*4..tp*4+3)
  const int tn = t >> 2;       // 0..47, candidates tn*3..tn*3+2

  float acc[4][3];
  #pragma unroll
  for (int ii = 0; ii < 4; ++ii) { acc[ii][0] = 0.f; acc[ii][1] = 0.f; acc[ii][2] = 0.f; }

  for (int kc = 0; kc < KFF; kc += FKB) {
    __syncthreads();
    // stage candidates: 144 rows x 8 float4 = 1152 f4, 6 per thread
    #pragma unroll
    for (int it = 0; it < 6; ++it) {
      int idx = it * 192 + t;
      int r = idx >> 3, f = idx & 7;
      float4 v = *(const float4*)(f1 + cOff[r] + kc + f*4);
      *(float4*)&cs[r][f*4] = v;
    }
    // stage queries: 16 rows x 8 float4 = 128 f4
    if (t < 128) {
      int r = t >> 3, f = t & 7;
      float4 v = *(const float4*)(fkf + qOff[r] + kc + f*4);
      *(float4*)&qs[r][f*4] = v;
    }
    __syncthreads();

    #pragma unroll
    for (int k4 = 0; k4 < FKB/4; ++k4) {
      float4 cv0 = *(const float4*)&cs[tn*3 + 0][k4*4];
      float4 cv1 = *(const float4*)&cs[tn*3 + 1][k4*4];
      float4 cv2 = *(const float4*)&cs[tn*3 + 2][k4*4];
      #pragma unroll
      for (int ii = 0; ii < 4; ++ii) {
        float4 qv = *(const float4*)&qs[tp*4 + ii][k4*4];
        acc[ii][0] = fmaf(qv.x, cv0.x, acc[ii][0]);
        acc[ii][0] = fmaf(qv.y, cv0.y, acc[ii][0]);
        acc[ii][0] = fmaf(qv.z, cv0.z, acc[ii][0]);
        acc[ii][0] = fmaf(qv.w, cv0.w, acc[ii][0]);
        acc[ii][1] = fmaf(qv.x, cv1.x, acc[ii][1]);
        acc[ii][1] = fmaf(qv.y, cv1.y, acc[ii][1]);
        acc[ii][1] = fmaf(qv.z, cv1.z, acc[ii][1]);
        acc[ii][1] = fmaf(qv.w, cv1.w, acc[ii][1]);
        acc[ii][2] = fmaf(qv.x, cv2.x, acc[ii][2]);
        acc[ii][2] = fmaf(qv.y, cv2.y, acc[ii][2]);
        acc[ii][2] = fmaf(qv.z, cv2.z, acc[ii][2]);
        acc[ii][2] = fmaf(qv.w, cv2.w, acc[ii][2]);
      }
    }
  }

  const float c20 = cn[tn*3 + 0], c21 = cn[tn*3 + 1], c22 = cn[tn*3 + 2];
  #pragma unroll
  for (int ii = 0; ii < 4; ++ii) {
    float q2 = q2s[tp*4 + ii];
    float bv = 3.0e38f; int bi = 0;
    float d0 = (q2 + c20) - 2.0f * acc[ii][0];
    float d1 = (q2 + c21) - 2.0f * acc[ii][1];
    float d2 = (q2 + c22) - 2.0f * acc[ii][2];
    if (d0 < bv) { bv = d0; bi = tn*3 + 0; }
    if (d1 < bv) { bv = d1; bi = tn*3 + 1; }
    if (d2 < bv) { bv = d2; bi = tn*3 + 2; }
    rbv[tp*4 + ii][tn] = bv;
    rbi[tp*4 + ii][tn] = bi;
  }
  __syncthreads();

  if (t < 16) {
    float v = rbv[t][0]; int ix = rbi[t][0];
    for (int s2 = 1; s2 < 48; ++s2) {
      float ov = rbv[t][s2];
      if (ov < v) { v = ov; ix = rbi[t][s2]; }   // ascending idx -> first-min
    }
    int n9 = ix >> 4, s3 = ix & 15;
    int br = cbr[n9]*DCC + (s3 >> 2);
    int bc = cbc[n9]*DCC + (s3 & 3);
    int fr = i*DCC + (t >> 2), fc = j*DCC + (t & 3);
    size_t ob = (((size_t)b*HFF + fr)*WFF + fc) * 2;
    outf[ob]     = br;
    outf[ob + 1] = bc;
  }
}

extern "C" void kernel_launch(void* const* d_in, const int* in_sizes, int n_in,
                              void* d_out, int out_size, void* d_ws, size_t ws_size,
                              hipStream_t stream) {
  (void)in_sizes; (void)n_in; (void)out_size; (void)ws_size;
  const float* f1c = (const float*)d_in[0];
  const float* fkc = (const float*)d_in[1];
  const float* f1f = (const float*)d_in[2];
  const float* fkf = (const float*)d_in[3];
  int* out = (int*)d_out;

  float* ws = (float*)d_ws;
  float* nq_c = ws;                        // 4096
  float* na_c = ws + 4096;                 // 4096
  float* nq_f = ws + 8192;                 // 65536
  float* na_f = ws + 8192 + 65536;         // 65536
  float* pval = ws + 8192 + 131072;        // 32768
  int*   pidx = (int*)(ws + 8192 + 131072 + 32768);

  // squared norms: coarse (k=1024) and fine (k=256)
  norms_kernel<<<dim3(BB*NCC/4, 2), 256, 0, stream>>>(fkc, f1c, nq_c, na_c, BB*NCC, KCC/4);
  norms_kernel<<<dim3(BB*HFF*WFF/4, 2), 256, 0, stream>>>(fkf, f1f, nq_f, na_f, BB*HFF*WFF, KFF/4);

  // coarse match
  coarse_kernel<<<dim3(NCHUNK, NCC/64, BB), 256, 0, stream>>>(f1c, fkc, na_c, nq_c, pval, pidx);
  coarse_reduce_kernel<<<dim3((BB*NCC + 255)/256), 256, 0, stream>>>(pval, pidx, out);

  // fine match (reads coarse result from d_out)
  fine_kernel<<<dim3(WCC, HCC, BB), 192, 0, stream>>>(f1f, fkf, na_f, nq_f, out, out + BB*HCC*WCC*2);
}

// Round 3
// 154.174 us; speedup vs baseline: 2.0339x; 2.0339x over previous
//
#include <hip/hip_runtime.h>
#include <cstdint>
#include <cstddef>

#define BB 4
#define HCC 32
#define WCC 32
#define KCC 1024
#define NCC (HCC*WCC)
#define HFF 128
#define WFF 128
#define KFF 256
#define DCC 4
#define NCHUNK 8

typedef _Float16 half8 __attribute__((ext_vector_type(8)));
typedef float f32x4 __attribute__((ext_vector_type(4)));
#define MFMA16(a,b,c) __builtin_amdgcn_mfma_f32_16x16x32_f16((a),(b),(c),0,0,0)
#define INV2K 0.00048828125f

// split fp32 -> (hi fp16, lo' = fp16(2048*(x-hi))).  dot = S1 + S2/2048.
__device__ inline void cvt8(const float4 u0, const float4 u1, half8& h, half8& l2) {
  float uu[8];
  *(float4*)uu = u0; *(float4*)(uu + 4) = u1;
  #pragma unroll
  for (int e = 0; e < 8; ++e) {
    _Float16 hh = (_Float16)uu[e];
    float r = (uu[e] - (float)hh) * 2048.0f;
    h[e] = hh; l2[e] = (_Float16)r;
  }
}

// ============ coarse: 128 cands x 64 queries per block, fp16x3 MFMA ============
// grid (8 m-chunks, 16 n-tiles, 4 b), 256 threads = 4 waves (2m x 2n), wave tile 64x32.
__global__ __launch_bounds__(256, 2) void coarse_kernel(
    const float* __restrict__ f1, const float* __restrict__ fk,
    float* __restrict__ pval, int* __restrict__ pidx) {
  // linear 128B rows, chunk-XOR swizzle (chunk = 16B): stored chunk = c ^ (row&7)
  __shared__ _Float16 Ahi[128][64], Alo[128][64];   // 16KB + 16KB
  __shared__ _Float16 Bhi[64][64],  Blo[64][64];    // 8KB + 8KB
  __shared__ float npA[256], npB[256];
  __shared__ float a2s[128], q2s[64];
  __shared__ float redv[2][64];
  __shared__ int   redi[2][64];

  const int t = threadIdx.x;
  const int chunk = blockIdx.x;
  const int n0 = blockIdx.y * 64;
  const int b  = blockIdx.z;
  const int m0 = chunk * 128;

  const float* __restrict__ Abase = f1 + ((size_t)b * NCC + m0) * KCC;  // candidates
  const float* __restrict__ Bbase = fk + ((size_t)b * NCC + n0) * KCC;  // queries

  // staging assignment (fixed per thread across fills -> per-thread norm partials)
  const int ar = t >> 1, ahf = t & 1;   // A: row 0..127, k-half (32 floats)
  const int brw = t >> 2, bq = t & 3;   // B: row 0..63,  k-quarter (16 floats)

  const int l  = t & 63;
  const int wv = t >> 6;
  const int wm = wv >> 1, wn = wv & 1;

  float nrmA = 0.f, nrmB = 0.f;
  f32x4 accA[4][2], accB[4][2];
  #pragma unroll
  for (int mt = 0; mt < 4; ++mt)
    #pragma unroll
    for (int nt = 0; nt < 2; ++nt) { accA[mt][nt] = (f32x4)0.f; accB[mt][nt] = (f32x4)0.f; }

  for (int k0 = 0; k0 < KCC; k0 += 64) {
    __syncthreads();
    // ---- stage A: 128 rows x 64 k (fp32 -> hi/lo planes), swizzled chunks ----
    {
      const float4* src = (const float4*)(Abase + (size_t)ar * KCC + k0 + ahf * 32);
      float4 va[8];
      #pragma unroll
      for (int i2 = 0; i2 < 8; ++i2) va[i2] = src[i2];
      #pragma unroll
      for (int i2 = 0; i2 < 8; ++i2)
        nrmA += va[i2].x*va[i2].x + va[i2].y*va[i2].y + va[i2].z*va[i2].z + va[i2].w*va[i2].w;
      #pragma unroll
      for (int c2 = 0; c2 < 4; ++c2) {
        half8 hh, hl;
        cvt8(va[c2*2], va[c2*2+1], hh, hl);
        int cs = (ahf * 4 + c2) ^ (ar & 7);
        *(half8*)&Ahi[ar][cs * 8] = hh;
        *(half8*)&Alo[ar][cs * 8] = hl;
      }
    }
    // ---- stage B: 64 rows x 64 k ----
    {
      const float4* src = (const float4*)(Bbase + (size_t)brw * KCC + k0 + bq * 16);
      float4 vb[4];
      #pragma unroll
      for (int i2 = 0; i2 < 4; ++i2) vb[i2] = src[i2];
      #pragma unroll
      for (int i2 = 0; i2 < 4; ++i2)
        nrmB += vb[i2].x*vb[i2].x + vb[i2].y*vb[i2].y + vb[i2].z*vb[i2].z + vb[i2].w*vb[i2].w;
      #pragma unroll
      for (int c2 = 0; c2 < 2; ++c2) {
        half8 hh, hl;
        cvt8(vb[c2*2], vb[c2*2+1], hh, hl);
        int cs = (bq * 2 + c2) ^ (brw & 7);
        *(half8*)&Bhi[brw][cs * 8] = hh;
        *(half8*)&Blo[brw][cs * 8] = hl;
      }
    }
    __syncthreads();

    // ---- MFMA: 2 ksteps of K=32 ----
    #pragma unroll
    for (int kk = 0; kk < 2; ++kk) {
      const int cs = ((kk * 4 + (l >> 4)) ^ (l & 7)) * 8;
      half8 ah[4], al[4], bh[2], bl[2];
      #pragma unroll
      for (int mt = 0; mt < 4; ++mt) {
        int row = wm * 64 + mt * 16 + (l & 15);
        ah[mt] = *(const half8*)&Ahi[row][cs];
        al[mt] = *(const half8*)&Alo[row][cs];
      }
      #pragma unroll
      for (int nt = 0; nt < 2; ++nt) {
        int row = wn * 32 + nt * 16 + (l & 15);
        bh[nt] = *(const half8*)&Bhi[row][cs];
        bl[nt] = *(const half8*)&Blo[row][cs];
      }
      #pragma unroll
      for (int mt = 0; mt < 4; ++mt)
        #pragma unroll
        for (int nt = 0; nt < 2; ++nt) {
          accA[mt][nt] = MFMA16(ah[mt], bh[nt], accA[mt][nt]);
          accB[mt][nt] = MFMA16(ah[mt], bl[nt], accB[mt][nt]);
          accB[mt][nt] = MFMA16(al[mt], bh[nt], accB[mt][nt]);
        }
    }
  }

  // ---- norms to LDS ----
  npA[t] = nrmA; npB[t] = nrmB;
  __syncthreads();
  if (t < 128) a2s[t] = npA[2*t] + npA[2*t + 1];
  if (t < 64)  q2s[t] = npB[4*t] + npB[4*t + 1] + npB[4*t + 2] + npB[4*t + 3];
  __syncthreads();

  // ---- epilogue: dist + argmin (first-index ties) ----
  #pragma unroll
  for (int nt = 0; nt < 2; ++nt) {
    float q2 = q2s[wn * 32 + nt * 16 + (l & 15)];
    float bv = 3.0e38f; int bi = 0;
    #pragma unroll
    for (int mt = 0; mt < 4; ++mt)
      #pragma unroll
      for (int r = 0; r < 4; ++r) {
        float dot = accA[mt][nt][r] + accB[mt][nt][r] * INV2K;
        int ml = wm * 64 + mt * 16 + (l >> 4) * 4 + r;
        float d = (q2 + a2s[ml]) - 2.0f * dot;
        if (d < bv) { bv = d; bi = m0 + ml; }
      }
    #pragma unroll
    for (int mm = 16; mm < 64; mm <<= 1) {
      float ov = __shfl_xor(bv, mm, 64);
      int oi = __shfl_xor(bi, mm, 64);
      if (ov < bv || (ov == bv && oi < bi)) { bv = ov; bi = oi; }
    }
    if ((l >> 4) == 0) { redv[wm][wn*32 + nt*16 + l] = bv; redi[wm][wn*32 + nt*16 + l] = bi; }
  }
  __syncthreads();
  if (t < 64) {
    float v0 = redv[0][t]; int i0 = redi[0][t];
    float v1 = redv[1][t]; int i1 = redi[1][t];
    if (v1 < v0) { v0 = v1; i0 = i1; }     // wm=1 has larger idx; strict < keeps first
    pval[((size_t)b * NCC + n0 + t) * NCHUNK + chunk] = v0;
    pidx[((size_t)b * NCC + n0 + t) * NCHUNK + chunk] = i0;
  }
}

// ============ coarse: combine chunk partials ============
__global__ __launch_bounds__(256) void coarse_reduce_kernel(
    const float* __restrict__ pval, const int* __restrict__ pidx,
    int* __restrict__ out) {
  int g = blockIdx.x * 256 + threadIdx.x;
  if (g >= BB * NCC) return;
  float bv = pval[(size_t)g * NCHUNK];
  int bi = pidx[(size_t)g * NCHUNK];
  #pragma unroll
  for (int c = 1; c < NCHUNK; ++c) {
    float v = pval[(size_t)g * NCHUNK + c];
    int ix = pidx[(size_t)g * NCHUNK + c];
    if (v < bv) { bv = v; bi = ix; }
  }
  out[(size_t)g*2]     = bi >> 5;
  out[(size_t)g*2 + 1] = bi & 31;
}

// ============ fine: per-cell 16q x 144c x k256, fp16x3 MFMA ============
// grid (32,32,4), 192 threads = 3 waves, wave = 3 cand-tiles of 16.
__global__ __launch_bounds__(192) void fine_kernel(
    const float* __restrict__ f1, const float* __restrict__ fkf,
    const int* __restrict__ coarse, int* __restrict__ outf) {
  __shared__ _Float16 Qhi[16][256], Qlo[16][256];   // 8KB + 8KB, chunk-XOR swizzled
  __shared__ float qn[16], cn[144];
  __shared__ int cROW[144];
  __shared__ int cbr[9], cbc[9];
  __shared__ float redv[3][16];
  __shared__ int   redi[3][16];

  const int t = threadIdx.x;
  const int j = blockIdx.x, i = blockIdx.y, b = blockIdx.z;
  const int l = t & 63, wv = t >> 6;

  if (t < 9) {
    int di = t / 3 - 1, dj = t % 3 - 1;
    int y = min(max(i + di, 0), HCC - 1);
    int x = min(max(j + dj, 0), WCC - 1);
    int base = ((b*HCC + y)*WCC + x) * 2;
    cbr[t] = coarse[base];
    cbc[t] = coarse[base + 1];
  }
  __syncthreads();
  if (t < 144) {
    int n9 = t >> 4, s = t & 15;
    int row = cbr[n9]*DCC + (s >> 2), col = cbc[n9]*DCC + (s & 3);
    cROW[t] = (b*HFF + row)*WFF + col;
  }
  // wave 0 stages queries (fp32 -> hi/lo planes) + query norms
  if (t < 64) {
    int qr = l & 15, qq = l >> 4;
    int fr = i*DCC + (qr >> 2), fc = j*DCC + (qr & 3);
    const float* src = fkf + ((size_t)(b*HFF + fr)*WFF + fc) * KFF + qq * 64;
    float s2 = 0.f;
    #pragma unroll
    for (int c2 = 0; c2 < 8; ++c2) {
      float4 u0 = *(const float4*)(src + c2*8);
      float4 u1 = *(const float4*)(src + c2*8 + 4);
      s2 += u0.x*u0.x + u0.y*u0.y + u0.z*u0.z + u0.w*u0.w
          + u1.x*u1.x + u1.y*u1.y + u1.z*u1.z + u1.w*u1.w;
      half8 hh, hl;
      cvt8(u0, u1, hh, hl);
      int cs = (qq * 8 + c2) ^ (qr & 7);
      *(half8*)&Qhi[qr][cs * 8] = hh;
      *(half8*)&Qlo[qr][cs * 8] = hl;
    }
    s2 += __shfl_xor(s2, 16, 64);
    s2 += __shfl_xor(s2, 32, 64);
    if (qq == 0) qn[qr] = s2;
  }
  __syncthreads();

  // main loop: 3 tiles per wave, frags gathered from global fp32 + converted
  const float* ap[3];
  #pragma unroll
  for (int T = 0; T < 3; ++T)
    ap[T] = f1 + (size_t)cROW[(wv*3 + T)*16 + (l & 15)] * KFF;

  f32x4 accA[3], accB[3];
  float nrmp[3];
  #pragma unroll
  for (int T = 0; T < 3; ++T) { accA[T] = (f32x4)0.f; accB[T] = (f32x4)0.f; nrmp[T] = 0.f; }

  #pragma unroll 2
  for (int s = 0; s < 8; ++s) {
    const int cs = ((s * 4 + (l >> 4)) ^ (l & 7)) * 8;
    half8 bh = *(const half8*)&Qhi[l & 15][cs];
    half8 bl = *(const half8*)&Qlo[l & 15][cs];
    #pragma unroll
    for (int T = 0; T < 3; ++T) {
      const float* p = ap[T] + s*32 + (l >> 4)*8;
      float4 u0 = *(const float4*)p;
      float4 u1 = *(const float4*)(p + 4);
      nrmp[T] += u0.x*u0.x + u0.y*u0.y + u0.z*u0.z + u0.w*u0.w
               + u1.x*u1.x + u1.y*u1.y + u1.z*u1.z + u1.w*u1.w;
      half8 ahv, alv;
      cvt8(u0, u1, ahv, alv);
      accA[T] = MFMA16(ahv, bh, accA[T]);
      accB[T] = MFMA16(ahv, bl, accB[T]);
      accB[T] = MFMA16(alv, bh, accB[T]);
    }
  }

  // candidate norms -> LDS (bitwise-consistent for duplicate rows)
  #pragma unroll
  for (int T = 0; T < 3; ++T) {
    float np = nrmp[T];
    np += __shfl_xor(np, 16, 64);
    np += __shfl_xor(np, 32, 64);
    if ((l >> 4) == 0) cn[(wv*3 + T)*16 + l] = np;
  }
  __syncthreads();

  // epilogue: dist + argmin (first-index ties)
  {
    float q2 = qn[l & 15];
    float bv = 3.0e38f; int bi = 0;
    #pragma unroll
    for (int T = 0; T < 3; ++T)
      #pragma unroll
      for (int r = 0; r < 4; ++r) {
        float dot = accA[T][r] + accB[T][r] * INV2K;
        int m = (wv*3 + T)*16 + (l >> 4)*4 + r;
        float d = (q2 + cn[m]) - 2.0f * dot;
        if (d < bv) { bv = d; bi = m; }
      }
    #pragma unroll
    for (int mm = 16; mm < 64; mm <<= 1) {
      float ov = __shfl_xor(bv, mm, 64);
      int oi = __shfl_xor(bi, mm, 64);
      if (ov < bv || (ov == bv && oi < bi)) { bv = ov; bi = oi; }
    }
    if ((l >> 4) == 0 && l < 16) { redv[wv][l] = bv; redi[wv][l] = bi; }
  }
  __syncthreads();

  if (t < 16) {
    float v = redv[0][t]; int ix = redi[0][t];
    #pragma unroll
    for (int w = 1; w < 3; ++w) {
      float ov = redv[w][t];
      if (ov < v) { v = ov; ix = redi[w][t]; }   // wave idx ranges ascending
    }
    int n9 = ix >> 4, s3 = ix & 15;
    int br = cbr[n9]*DCC + (s3 >> 2);
    int bc = cbc[n9]*DCC + (s3 & 3);
    int fr = i*DCC + (t >> 2), fc = j*DCC + (t & 3);
    size_t ob = ((size_t)(b*HFF + fr)*WFF + fc) * 2;
    outf[ob]     = br;
    outf[ob + 1] = bc;
  }
}

extern "C" void kernel_launch(void* const* d_in, const int* in_sizes, int n_in,
                              void* d_out, int out_size, void* d_ws, size_t ws_size,
                              hipStream_t stream) {
  (void)in_sizes; (void)n_in; (void)out_size; (void)ws_size;
  const float* f1c = (const float*)d_in[0];
  const float* fkc = (const float*)d_in[1];
  const float* f1f = (const float*)d_in[2];
  const float* fkf = (const float*)d_in[3];
  int* out = (int*)d_out;

  float* pval = (float*)d_ws;                       // 4*1024*8
  int*   pidx = (int*)((float*)d_ws + BB*NCC*NCHUNK);

  coarse_kernel<<<dim3(NCHUNK, NCC/64, BB), 256, 0, stream>>>(f1c, fkc, pval, pidx);
  coarse_reduce_kernel<<<dim3((BB*NCC + 255)/256), 256, 0, stream>>>(pval, pidx, out);
  fine_kernel<<<dim3(WCC, HCC, BB), 192, 0, stream>>>(f1f, fkf, out, out + BB*HCC*WCC*2);
}